// Round 1
// baseline (71.948 us; speedup 1.0000x reference)
//
#include <hip/hip_runtime.h>
#include <math.h>

// QuanvolutionHybrid: closed-form collapse of the quantum circuit.
// Per patch p (2x2 pixels d0..d3), per qubit k:
//   E_k = cos(beta_k)*cos(2*d_k) - cos(alpha_k)*sin(beta_k)*sin(2*d_k)
// feats[4p+0..3] = [E0, E0*E1, E2, E2*E3]
// logits = feats @ W^T + b ; out = log_softmax(logits)
//
// v2: occupancy/latency attack. Previous version: 1 wave per image -> grid
// is exactly ONE round of 4 waves/SIMD (16/CU), so total time ~= one wave's
// critical path with minimal latency hiding. Now: 2 waves per image (98
// patches each, 2 k-iters instead of 4), 8192 waves total -> 8 waves/SIMD
// target via __launch_bounds__(256, 8) (VGPR <= 64). Cross-wave combine via
// 160 B LDS + one barrier; per-image softmax finalized by one thread each.

__global__ __launch_bounds__(256, 8) void quanv_kernel(
    const float* __restrict__ x,       // (4096, 784) flat
    const float* __restrict__ params,  // (8,)
    const float* __restrict__ W,       // (10, 784)
    const float* __restrict__ bias,    // (10,)
    float* __restrict__ out)           // (4096, 10)
{
    const int t = threadIdx.x;
    const int wave = t >> 6;            // 0..3
    const int lane = t & 63;
    const int img_in_blk = wave >> 1;   // 0..1  (2 images per block)
    const int half = wave & 1;          // which half of the image's patches
    const int b = blockIdx.x * 2 + img_in_blk;

    // Per-qubit coefficients (lane-uniform)
    float A[4], Bc[4];
#pragma unroll
    for (int k = 0; k < 4; k++) {
        const float al = params[2 * k];
        const float be = params[2 * k + 1];
        A[k]  = __cosf(be);
        Bc[k] = __sinf(be) * __cosf(al);
    }

    const float* img = x + (size_t)b * 784;
    const float4* W4 = (const float4*)W;   // [c][196] float4 rows

    float lg[10];
#pragma unroll
    for (int c = 0; c < 10; c++) lg[c] = 0.0f;

    // This wave covers patches [98*half, 98*half + 98): 64 + 34 (masked).
#pragma unroll
    for (int k = 0; k < 2; k++) {
        const int off = 64 * k + lane;            // 0..127
        const bool valid = (off < 98);
        const int p = half * 98 + (valid ? off : 97);  // clamp keeps loads in-bounds
        const int i = p / 14;
        const int j = p - 14 * i;

        const float2 d01 = *(const float2*)(img + i * 56 + 2 * j);
        const float2 d23 = *(const float2*)(img + i * 56 + 28 + 2 * j);

        const float E0 = A[0] * __cosf(2.0f * d01.x) - Bc[0] * __sinf(2.0f * d01.x);
        const float E1 = A[1] * __cosf(2.0f * d01.y) - Bc[1] * __sinf(2.0f * d01.y);
        const float E2 = A[2] * __cosf(2.0f * d23.x) - Bc[2] * __sinf(2.0f * d23.x);
        const float E3 = A[3] * __cosf(2.0f * d23.y) - Bc[3] * __sinf(2.0f * d23.y);

        const float f0 = valid ? E0 : 0.0f;
        const float f1 = f0 * E1;
        const float f2 = valid ? E2 : 0.0f;
        const float f3 = f2 * E3;

        // Two 5-class groups: caps W-loads in flight at 5 float4 (20 VGPR)
        // so the (256,8) bound (64 VGPR) holds without spill.
#pragma unroll
        for (int c = 0; c < 5; c++) {
            const float4 w = W4[c * 196 + p];
            lg[c] += f0 * w.x + f1 * w.y + f2 * w.z + f3 * w.w;
        }
#pragma unroll
        for (int c = 5; c < 10; c++) {
            const float4 w = W4[c * 196 + p];
            lg[c] += f0 * w.x + f1 * w.y + f2 * w.z + f3 * w.w;
        }
    }

    // Wave butterfly reduction of 10 partial logits (valid in lane 0).
#pragma unroll
    for (int c = 0; c < 10; c++) {
        float v = lg[c];
#pragma unroll
        for (int o = 32; o > 0; o >>= 1) v += __shfl_down(v, o, 64);
        lg[c] = v;
    }

    __shared__ float ls[4][10];
    if (lane == 0) {
#pragma unroll
        for (int c = 0; c < 10; c++) ls[wave][c] = lg[c];
    }
    __syncthreads();

    // One thread per image finalizes: combine halves, bias, log_softmax.
    if (t < 2) {
        float l[10];
        float mx = -1e30f;
#pragma unroll
        for (int c = 0; c < 10; c++) {
            l[c] = ls[2 * t][c] + ls[2 * t + 1][c] + bias[c];
            mx = fmaxf(mx, l[c]);
        }
        float sum = 0.0f;
#pragma unroll
        for (int c = 0; c < 10; c++) sum += __expf(l[c] - mx);
        const float lse = mx + __logf(sum);
        float* ob = out + ((size_t)blockIdx.x * 2 + t) * 10;
#pragma unroll
        for (int c = 0; c < 10; c++) ob[c] = l[c] - lse;
    }
}

extern "C" void kernel_launch(void* const* d_in, const int* in_sizes, int n_in,
                              void* d_out, int out_size, void* d_ws, size_t ws_size,
                              hipStream_t stream) {
    const float* x      = (const float*)d_in[0];  // 4096*784
    const float* params = (const float*)d_in[1];  // 8
    const float* W      = (const float*)d_in[2];  // 10*784
    const float* bias   = (const float*)d_in[3];  // 10
    float* out          = (float*)d_out;          // 4096*10

    quanv_kernel<<<2048, 256, 0, stream>>>(x, params, W, bias, out);
}